// Round 10
// baseline (3402.720 us; speedup 1.0000x reference)
//
#include <hip/hip_runtime.h>

#define NB 32
#define NP 65536
#define NS 1024
#define NT 1024
#define BPB 8                 // blocks per batch
#define CHUNK (NP / BPB)      // 8192 points per block
#define PPT (CHUNK / NT)      // 8 points per thread
#define FAST_ATT 24           // bounded sc0 poll attempts
#define DEMOTE_AFTER 2        // consecutive fast-timeouts -> lane safe-only

typedef unsigned long long u64;
typedef unsigned int u32;
typedef int int4v __attribute__((ext_vector_type(4)));

// ---------------- R10: R7 control flow + XCD-local fast poll ----------------
// Slot (b,s,j) = 32B, written ONCE per launch: h0={tag=s,keyhi,keylo,x},
// h1={tag=s,y,z,0}. Valid iff h0.tag==s && h1.tag==s (rejects memset-0 and
// 0xAA poison; stale tag-s lines are bit-identical by determinism -> benign).
// CONTROL FLOW RULE (R8/R9 deadlock lesson): the slot store is a separate,
// loop-free `if (lane==0)` statement that COMPLETES before any poll loop
// starts. Never put an unbounded poll in the else of the writer's branch:
// exec-mask serialization can run the spinning side first and the same-wave
// store never issues -> global deadlock.
__global__ __launch_bounds__(NT) void fps_v10(const float* __restrict__ pts,
                                              float* __restrict__ out,
                                              u32* __restrict__ slots) {
#pragma clang fp contract(off)
    const int bid = blockIdx.x;
    const int b = bid & 31;           // batch: its 8 blocks are bid == b (mod 32)
    const int j = bid >> 5;           //   -> all share bid%8 (same XCD if rr)
    const int t = threadIdx.x;
    const int wave = t >> 6;
    const int lane = t & 63;
    const int base = j * CHUNK;
    const float* __restrict__ pb = pts + (size_t)b * NP * 3;
    float* __restrict__ out_idx = out + (size_t)b * NS;
    float* __restrict__ out_pts = out + (size_t)NB * NS + (size_t)b * NS * 3;
    u32* __restrict__ slot_b = slots + (size_t)b * NS * BPB * 8;  // u32 words

    __shared__ float P[CHUNK * 3];    // 96 KB packed points
    __shared__ u64 cand[NT / 64];
    __shared__ int sel_hist[NS];
    __shared__ float qsh[3];

    // stage chunk into LDS, coalesced float4
    {
        const float4* __restrict__ src4 = (const float4*)(pb + (size_t)base * 3);
        float4* dst4 = (float4*)P;
#pragma unroll
        for (int k = 0; k < (CHUNK * 3 / 4) / NT; ++k) dst4[t + k * NT] = src4[t + k * NT];
    }
    if (t == 0) {
        sel_hist[0] = 0;
        if (j == 0) out_idx[0] = 0.0f;
        qsh[0] = pb[0]; qsh[1] = pb[1]; qsh[2] = pb[2];   // first sel = point 0
    }
    __syncthreads();

    // points -> registers, CONSECUTIVE per-thread range [t*8, t*8+8):
    // lowest lane then == lowest global idx (exact ballot tie-break)
    float px[PPT], py[PPT], pz[PPT], md[PPT];
#pragma unroll
    for (int i = 0; i < PPT; ++i) {
        const int li = t * PPT + i;
        px[i] = P[li * 3 + 0];
        py[i] = P[li * 3 + 1];
        pz[i] = P[li * 3 + 2];
        md[i] = 1e10f;
    }
    float qx = qsh[0], qy = qsh[1], qz = qsh[2];

    int usefast = 1, fastfail = 0;    // per-lane poll mode (wave0 lanes 0-7)

    for (int s = 1; s < NS; ++s) {
        float bv = -1.0f;
        int bi = 0;
#pragma unroll
        for (int i = 0; i < PPT; ++i) {
            float dx = px[i] - qx;
            float dy = py[i] - qy;
            float dz = pz[i] - qz;
            float d = (dx * dx + dy * dy) + dz * dz;   // match np reduce order
            float nmd = fminf(md[i], d);
            md[i] = nmd;
            if (nmd > bv) { bv = nmd; bi = t * PPT + i; }  // strict >: min idx
        }
        // wave argmax: f32 max reduce; ballot lowest lane among ties == min idx
        float m = bv;
#pragma unroll
        for (int d1 = 32; d1 >= 1; d1 >>= 1) m = fmaxf(m, __shfl_xor(m, d1, 64));
        u64 msk = __ballot(bv == m);
        int src = __ffsll((unsigned long long)msk) - 1;
        int biw = __shfl(bi, src, 64);
        if (lane == 0)
            cand[wave] = ((u64)__float_as_uint(m) << 32) |
                         (u64)(0xFFFFFFFFu - (u32)(base + biw));
        __syncthreads();
        if (wave == 0) {
            // stage-2: all lanes reduce the 16 wave candidates
            u64 c = cand[lane & 15];
#pragma unroll
            for (int d1 = 8; d1 >= 1; d1 >>= 1) {
                u64 o = __shfl_xor(c, d1, 64);
                c = (o > c) ? o : c;
            }
            // ---- writer: separate, loop-free, completes before polls ----
            const int g0 = (int)(0xFFFFFFFFu - (u32)(c & 0xFFFFFFFFull));
            float wx0 = 0.f, wy0 = 0.f, wz0 = 0.f;
            if (lane == 0) {
                const int lw = g0 - base;
                wx0 = P[lw * 3 + 0];
                wy0 = P[lw * 3 + 1];
                wz0 = P[lw * 3 + 2];
                int4v h0, h1;
                h0.x = s;                         // tag (both halves)
                h0.y = (int)(u32)(c >> 32);       // key hi = valbits
                h0.z = (int)(u32)c;               // key lo = ~idx
                h0.w = __float_as_int(wx0);
                h1.x = s;
                h1.y = __float_as_int(wy0);
                h1.z = __float_as_int(wz0);
                h1.w = 0;
                u32* sp = slot_b + ((size_t)s * BPB + j) * 8;
                asm volatile(
                    "global_store_dwordx4 %0, %2, off sc0 sc1\n\t"
                    "global_store_dwordx4 %1, %3, off sc0 sc1\n\t"
                    "global_store_dwordx4 %0, %2, off sc0\n\t"
                    "global_store_dwordx4 %1, %3, off sc0"
                    :: "v"(sp), "v"(sp + 4), "v"(h0), "v"(h1) : "memory");
            }
            // ---- pollers: fast bounded sc0, then proven sc0sc1 loop ----
            if (lane < BPB) {
                u64 k = c;                        // lane j keeps own candidate
                float wx = 0.f, wy = 0.f, wz = 0.f;
                if (lane != j) {
                    const u32* sp = slot_b + ((size_t)s * BPB + lane) * 8;
                    int4v a, bb;
                    int got = 0;
                    if (usefast) {
                        for (int it = 0; it < FAST_ATT && !got; ++it) {
                            asm volatile(
                                "global_load_dwordx4 %0, %2, off sc0\n\t"
                                "global_load_dwordx4 %1, %3, off sc0\n\t"
                                "s_waitcnt vmcnt(0)"
                                : "=&v"(a), "=&v"(bb)
                                : "v"(sp), "v"(sp + 4) : "memory");
                            got = (a.x == s && bb.x == s);
                        }
                        if (got) fastfail = 0;
                        else if (++fastfail >= DEMOTE_AFTER) usefast = 0;
                    }
                    if (!got) {
                        for (;;) {   // R7-proven terminating (sc0 sc1 world)
                            asm volatile(
                                "global_load_dwordx4 %0, %2, off sc0 sc1\n\t"
                                "global_load_dwordx4 %1, %3, off sc0 sc1\n\t"
                                "s_waitcnt vmcnt(0)"
                                : "=&v"(a), "=&v"(bb)
                                : "v"(sp), "v"(sp + 4) : "memory");
                            if (a.x == s && bb.x == s) break;
                        }
                    }
                    k = ((u64)(u32)a.y << 32) | (u32)a.z;
                    wx = __int_as_float(a.w);
                    wy = __int_as_float(bb.y);
                    wz = __int_as_float(bb.z);
                }
                // reduce over the 8 participants (lanes 0-7)
#pragma unroll
                for (int d1 = 4; d1 >= 1; d1 >>= 1) {
                    u64 o = __shfl_xor(k, d1, 64);
                    k = (o > k) ? o : k;
                }
                const int g = (int)(0xFFFFFFFFu - (u32)(k & 0xFFFFFFFFull));
                const int jw = (g >> 13) & 7;      // owning block (CHUNK=2^13)
                float sx = __shfl(wx, jw, 64);
                float sy = __shfl(wy, jw, 64);
                float sz = __shfl(wz, jw, 64);
                if (lane == 0) {
                    sel_hist[s] = g;
                    if (jw == j) { qsh[0] = wx0; qsh[1] = wy0; qsh[2] = wz0; }
                    else         { qsh[0] = sx;  qsh[1] = sy;  qsh[2] = sz;  }
                    if (j == 0) out_idx[s] = (float)g;
                }
            }
        }
        __syncthreads();
        qx = qsh[0]; qy = qsh[1]; qz = qsh[2];
    }

    if (j == 0) {
        const int gi = sel_hist[t];
        const float* __restrict__ p = pb + (size_t)gi * 3;
        out_pts[(size_t)t * 3 + 0] = p[0];
        out_pts[(size_t)t * 3 + 1] = p[1];
        out_pts[(size_t)t * 3 + 2] = p[2];
    }
}

// ---------------- R5 fallback: verified slot-store protocol (2 MB ws) -------
__global__ __launch_bounds__(NT) void fps_slots(const float* __restrict__ pts,
                                                float* __restrict__ out,
                                                u64* __restrict__ slots) {
#pragma clang fp contract(off)
    const int bid = blockIdx.x;
    const int b = bid >> 3;
    const int j = bid & 7;
    const int t = threadIdx.x;
    const int base = j * CHUNK;
    const float* __restrict__ pb = pts + (size_t)b * NP * 3;
    float* __restrict__ out_idx = out + (size_t)b * NS;
    float* __restrict__ out_pts = out + (size_t)NB * NS + (size_t)b * NS * 3;
    u64* __restrict__ slot_b = slots + (size_t)b * NS * BPB;

    __shared__ float P[CHUNK * 3];
    __shared__ u64 cand[NT / 64];
    __shared__ int sel_hist[NS];
    __shared__ float qsh[3];

    {
        const float4* __restrict__ src4 = (const float4*)(pb + (size_t)base * 3);
        float4* dst4 = (float4*)P;
#pragma unroll
        for (int k = 0; k < (CHUNK * 3 / 4) / NT; ++k) dst4[t + k * NT] = src4[t + k * NT];
    }
    float md[PPT];
#pragma unroll
    for (int i = 0; i < PPT; ++i) md[i] = 1e10f;
    if (t == 0) {
        sel_hist[0] = 0;
        if (j == 0) out_idx[0] = 0.0f;
        qsh[0] = pb[0]; qsh[1] = pb[1]; qsh[2] = pb[2];
    }
    __syncthreads();
    float qx = qsh[0], qy = qsh[1], qz = qsh[2];
    const int wave = t >> 6;
    const int lane = t & 63;
    for (int s = 1; s < NS; ++s) {
        float bestv = -1.0f;
        int besti = 0;
#pragma unroll
        for (int i = 0; i < PPT; ++i) {
            const int li = t + i * NT;
            const float* __restrict__ p = P + li * 3;
            float dx = p[0] - qx, dy = p[1] - qy, dz = p[2] - qz;
            float d = (dx * dx + dy * dy) + dz * dz;
            float nmd = fminf(md[i], d);
            md[i] = nmd;
            if (nmd > bestv) { bestv = nmd; besti = li; }
        }
        u64 pk = ((u64)__float_as_uint(bestv) << 32) |
                 (u64)(0xFFFFFFFFu - (u32)(base + besti));
#pragma unroll
        for (int m = 32; m >= 1; m >>= 1) {
            u64 o = __shfl_xor(pk, m, 64);
            pk = (o > pk) ? o : pk;
        }
        if (lane == 0) cand[wave] = pk;
        __syncthreads();
        if (wave == 0) {
            u64 c = (lane < 16) ? cand[lane] : 0ull;
#pragma unroll
            for (int m = 8; m >= 1; m >>= 1) {
                u64 o = __shfl_xor(c, m, 64);
                c = (o > c) ? o : c;
            }
            if (lane == 0) {
                __hip_atomic_store(&slot_b[(size_t)s * BPB + j], c,
                                   __ATOMIC_RELAXED, __HIP_MEMORY_SCOPE_AGENT);
            }
            u64 x = 0;
            if (lane < BPB) {
                const u64* sp = &slot_b[(size_t)s * BPB + lane];
                while ((x = __hip_atomic_load(sp, __ATOMIC_RELAXED,
                                              __HIP_MEMORY_SCOPE_AGENT)) == 0ull) {
                    __builtin_amdgcn_s_sleep(1);
                }
            }
#pragma unroll
            for (int m = 4; m >= 1; m >>= 1) {
                u64 o = __shfl_xor(x, m, 64);
                x = (o > x) ? o : x;
            }
            if (lane == 0) {
                int w = (int)(0xFFFFFFFFu - (u32)(x & 0xFFFFFFFFull));
                sel_hist[s] = w;
                const float* __restrict__ q = pb + (size_t)w * 3;
                qsh[0] = q[0]; qsh[1] = q[1]; qsh[2] = q[2];
                if (j == 0) out_idx[s] = (float)w;
            }
        }
        __syncthreads();
        qx = qsh[0]; qy = qsh[1]; qz = qsh[2];
    }
    if (j == 0) {
        const int gi = sel_hist[t];
        const float* __restrict__ p = pb + (size_t)gi * 3;
        out_pts[(size_t)t * 3 + 0] = p[0];
        out_pts[(size_t)t * 3 + 1] = p[1];
        out_pts[(size_t)t * 3 + 2] = p[2];
    }
}

extern "C" void kernel_launch(void* const* d_in, const int* in_sizes, int n_in,
                              void* d_out, int out_size, void* d_ws, size_t ws_size,
                              hipStream_t stream) {
    const float* pts = (const float*)d_in[0];
    float* out = (float*)d_out;
    (void)in_sizes; (void)n_in; (void)out_size;

    const size_t v10_bytes = (size_t)NB * NS * BPB * 32;            // 8 MB
    const size_t slot_bytes = (size_t)NB * NS * BPB * sizeof(u64);  // 2 MB
    if (ws_size >= v10_bytes) {
        u32* slots = (u32*)d_ws;
        hipMemsetAsync(d_ws, 0, v10_bytes, stream);
        void* args[] = {(void*)&pts, (void*)&out, (void*)&slots};
        hipLaunchCooperativeKernel((const void*)fps_v10, dim3(NB * BPB), dim3(NT),
                                   args, 0, stream);
    } else {
        u64* slots = (u64*)d_ws;
        hipMemsetAsync(d_ws, 0, slot_bytes, stream);
        void* args[] = {(void*)&pts, (void*)&out, (void*)&slots};
        hipLaunchCooperativeKernel((const void*)fps_slots, dim3(NB * BPB), dim3(NT),
                                   args, 0, stream);
    }
}